// Round 8
// baseline (603.893 us; speedup 1.0000x reference)
//
#include <hip/hip_runtime.h>
#include <math.h>

#define LEVELS 16
#define TBL 524288          // 2^19 entries per level
#define TMASK (TBL - 1)

typedef short bf16x8 __attribute__((ext_vector_type(8)));
typedef float f32x4  __attribute__((ext_vector_type(4)));

static __device__ __forceinline__ unsigned short f2bf(float x) {
    unsigned u = __float_as_uint(x);
    u += 0x7fffu + ((u >> 16) & 1u);    // RNE
    return (unsigned short)(u >> 16);
}
static __device__ __forceinline__ float b2f(unsigned short h) {
    return __uint_as_float(((unsigned)h) << 16);
}

// SH degree-4 block, constants computed exactly as round-1 (verified correct).
#define SH_BLOCK(sh, dx, dy, dz)                                                          \
    const float x2 = dx * dx, y2 = dy * dy, z2 = dz * dz;                                 \
    const float xy = dx * dy, xz = dx * dz, yz = dy * dz;                                 \
    const float x4 = x2 * x2, y4 = y2 * y2;                                               \
    const float c0  = (float)(0.5 * sqrt(1.0 / M_PI));                                    \
    const float c1  = (float)(0.5 * sqrt(3.0 / M_PI));                                    \
    const float sub = (float)(0.25 * sqrt(5.0 / M_PI));                                   \
    const float v1  = (float)(0.25 * sqrt(15.0 / M_PI));                                  \
    const float v2  = (float)(0.5 * sqrt(15.0 / M_PI));                                   \
    const float v3  = (float)(0.75 * sqrt(5.0 / M_PI));                                   \
    const float w1c = (float)(0.25 * sqrt(105.0 / M_PI));                                 \
    const float w2c = (float)(0.5 * sqrt(105.0 / M_PI));                                  \
    const float w3c = (float)(0.25 * sqrt(35.0 / (2.0 * M_PI)));                          \
    const float w4c = (float)(0.5 * sqrt(7.0 / (6.0 * M_PI)));                            \
    sh[0] = c0;                                                                           \
    sh[1] = -c1 * dy;                                                                     \
    sh[2] =  c1 * dz;                                                                     \
    sh[3] = -c1 * dx;                                                                     \
    sh[4] =  v2 * xy;                                                                     \
    sh[5] = -v2 * yz;                                                                     \
    sh[6] =  v3 * z2 - sub;                                                               \
    sh[7] = -v2 * xz;                                                                     \
    sh[8] =  v1 * x2 - v1 * y2;                                                           \
    sh[9]  = -w3c * dy * (3.0f * x2 - y2);                                                \
    sh[10] =  w2c * xy * dz;                                                              \
    sh[11] =  w4c * dy * (1.5f - 7.5f * z2);                                              \
    sh[12] =  1.24392110863372f * dz * (1.5f * z2 - 0.5f) - 0.497568443453487f * dz;      \
    sh[13] =  w4c * dx * (1.5f - 7.5f * z2);                                              \
    sh[14] =  w1c * dz * (x2 - y2);                                                       \
    sh[15] = -w3c * dx * (x2 - 3.0f * y2);                                                \
    sh[16] =  2.5033429417967f * xy * (x2 - y2);                                          \
    sh[17] = -1.77013076977993f * yz * (3.0f * x2 - y2);                                  \
    sh[18] =  0.126156626101008f * xy * (52.5f * z2 - 7.5f);                              \
    sh[19] =  0.267618617422916f * dy * (2.33333333333333f * dz * (1.5f - 7.5f * z2) + 4.0f * dz); \
    sh[20] =  1.48099765681286f * dz * (1.66666666666667f * dz * (1.5f * z2 - 0.5f) - 0.666666666666667f * dz) \
              - 0.952069922236839f * z2 + 0.317356640745613f;                             \
    sh[21] =  0.267618617422916f * dx * (2.33333333333333f * dz * (1.5f - 7.5f * z2) + 4.0f * dz); \
    sh[22] =  0.063078313050504f * (x2 - y2) * (52.5f * z2 - 7.5f);                       \
    sh[23] = -1.77013076977993f * xz * (x2 - 3.0f * y2);                                  \
    sh[24] = -3.75501441269506f * x2 * y2 + 0.625835735449176f * x4 + 0.625835735449176f * y4;

// ------------------------------------------------------------------
// Kernel 1: hash-grid gather with level<->XCD affinity (unchanged R6).
// ------------------------------------------------------------------
__global__ __launch_bounds__(256)
void ngp_encode_lvl(const float* __restrict__ pos,
                    const float* __restrict__ tables,
                    float2* __restrict__ ws2, int n)
{
    const int b = blockIdx.x;
    const int p = b & 7;
    const int h = b >> 14;                 // 16384 blocks per half (n = 2^19)
    const int l = 2 * p + h;
    const int c = (b & 16383) >> 3;
    const int idx = c * 256 + threadIdx.x;
    if (idx >= n || l >= LEVELS) return;

    const float px = pos[3 * idx + 0];
    const float py = pos[3 * idx + 1];
    const float pz = pos[3 * idx + 2];

    const float resf = (float)(16 << l);
    const float tx = px * resf, ty = py * resf, tz = pz * resf;
    const float fx = floorf(tx), fy = floorf(ty), fz = floorf(tz);
    const float wx = tx - fx, wy = ty - fy, wz = tz - fz;
    const unsigned ix = (unsigned)(int)fx;
    const unsigned iy = (unsigned)(int)fy;
    const unsigned iz = (unsigned)(int)fz;
    const unsigned hy0 = iy * 2654435761u, hy1 = hy0 + 2654435761u;
    const unsigned hz0 = iz * 805459861u,  hz1 = hz0 + 805459861u;
    const unsigned ix1 = ix + 1u;

    const float2* tb = (const float2*)tables + (size_t)l * TBL;
    const float2 e000 = tb[(ix  ^ hy0 ^ hz0) & TMASK];
    const float2 e001 = tb[(ix  ^ hy0 ^ hz1) & TMASK];
    const float2 e010 = tb[(ix  ^ hy1 ^ hz0) & TMASK];
    const float2 e011 = tb[(ix  ^ hy1 ^ hz1) & TMASK];
    const float2 e100 = tb[(ix1 ^ hy0 ^ hz0) & TMASK];
    const float2 e101 = tb[(ix1 ^ hy0 ^ hz1) & TMASK];
    const float2 e110 = tb[(ix1 ^ hy1 ^ hz0) & TMASK];
    const float2 e111 = tb[(ix1 ^ hy1 ^ hz1) & TMASK];

    const float ux = 1.f - wx, uy = 1.f - wy, uz = 1.f - wz;
    const float c000 = ux * uy * uz, c001 = ux * uy * wz;
    const float c010 = ux * wy * uz, c011 = ux * wy * wz;
    const float c100 = wx * uy * uz, c101 = wx * uy * wz;
    const float c110 = wx * wy * uz, c111 = wx * wy * wz;

    float f0 = e000.x * c000, f1 = e000.y * c000;
    f0 = fmaf(e001.x, c001, f0); f1 = fmaf(e001.y, c001, f1);
    f0 = fmaf(e010.x, c010, f0); f1 = fmaf(e010.y, c010, f1);
    f0 = fmaf(e011.x, c011, f0); f1 = fmaf(e011.y, c011, f1);
    f0 = fmaf(e100.x, c100, f0); f1 = fmaf(e100.y, c100, f1);
    f0 = fmaf(e101.x, c101, f0); f1 = fmaf(e101.y, c101, f1);
    f0 = fmaf(e110.x, c110, f0); f1 = fmaf(e110.y, c110, f1);
    f0 = fmaf(e111.x, c111, f0); f1 = fmaf(e111.y, c111, f1);

    ws2[(size_t)l * n + idx] = make_float2(f0, f1);
}

// ------------------------------------------------------------------
// Kernel 2: split-precision MFMA MLP.
// Block = 256 thr = 4 waves; wave = 16 points.
// rgb-path weights (Wc1/2/3) staged as bf16 hi+lo pairs; activations
// kept fp32 in LDS, split to hi/lo bf16 in registers at A-frag load.
// D = Ah*Bh + Al*Bh + Ah*Bl  (3-term; ~2^-16 relative).
// sigma path (d1/d2) single bf16 (activations ~1e-4, abs-safe).
// ------------------------------------------------------------------
#define MT   256
#define SW1  32                  // Wd1 k-stride (shorts), rows 16B-aligned
#define SW   72                  // 64-k weight stride (shorts), rows 16B-aligned
#define SA   66                  // act k-stride (floats)
#define OW1  0                   // 64*32 = 2048
#define OW2  2048                // 16*72 = 1152
#define OC1H 3200                // 64*72 = 4608
#define OC1L 7808
#define OC2H 12416
#define OC2L 17024
#define OC3H 21632               // 16*72 = 1152
#define OC3L 22784
#define WTOT 23936               // shorts = 47872 B; + act 16896 B = 64768 B

__global__ __launch_bounds__(256, 2)
void ngp_mlp_mfma2(const float2* __restrict__ ws2,
                   const float* __restrict__ dirp,
                   const float* __restrict__ Wd1, const float* __restrict__ bd1,
                   const float* __restrict__ Wd2, const float* __restrict__ bd2,
                   const float* __restrict__ Wc1, const float* __restrict__ bc1,
                   const float* __restrict__ Wc2, const float* __restrict__ bc2,
                   const float* __restrict__ Wc3, const float* __restrict__ bc3,
                   float* __restrict__ out, int n)
{
    __shared__ short wsm[WTOT];
    __shared__ float act[4 * 16 * SA];
    const int tid = threadIdx.x;

    for (int t = tid; t < WTOT; t += MT) wsm[t] = 0;
    __syncthreads();

    for (int g = tid; g < 32 * 64; g += MT) {            // Wd1 (32,64) single
        const int k = g >> 6, nn = g & 63;
        wsm[OW1 + nn * SW1 + k] = f2bf(Wd1[g]);
    }
    for (int g = tid; g < 64 * 16; g += MT) {            // Wd2 (64,16) single
        const int k = g >> 4, nn = g & 15;
        wsm[OW2 + nn * SW + k] = f2bf(Wd2[g]);
    }
    for (int g = tid; g < 41 * 64; g += MT) {            // Wc1 (41,64) hi+lo
        const int k = g >> 6, nn = g & 63;
        const float w = Wc1[g];
        const unsigned short hh = f2bf(w);
        wsm[OC1H + nn * SW + k] = hh;
        wsm[OC1L + nn * SW + k] = f2bf(w - b2f(hh));
    }
    for (int g = tid; g < 64 * 64; g += MT) {            // Wc2 (64,64) hi+lo
        const int k = g >> 6, nn = g & 63;
        const float w = Wc2[g];
        const unsigned short hh = f2bf(w);
        wsm[OC2H + nn * SW + k] = hh;
        wsm[OC2L + nn * SW + k] = f2bf(w - b2f(hh));
    }
    for (int g = tid; g < 64 * 3; g += MT) {             // Wc3 (64,3) hi+lo
        const int k = g / 3, nn = g - 3 * k;
        const float w = Wc3[g];
        const unsigned short hh = f2bf(w);
        wsm[OC3H + nn * SW + k] = hh;
        wsm[OC3L + nn * SW + k] = f2bf(w - b2f(hh));
    }
    __syncthreads();

    const int wid = tid >> 6;
    const int lane = tid & 63;
    const int ln = lane & 15;
    const int qd = lane >> 4;
    const int pt_base = blockIdx.x * 64 + wid * 16;
    const int pt = pt_base + ln;
    float* A = act + wid * (16 * SA);

    // ---- d1: Y[16x64] = X @ Wd1 (single bf16) ----
    bf16x8 ax;
#pragma unroll
    for (int s = 0; s < 4; ++s) {
        const float2 q = ws2[(size_t)(qd * 4 + s) * n + pt];
        ax[2 * s + 0] = (short)f2bf(q.x);
        ax[2 * s + 1] = (short)f2bf(q.y);
    }
    f32x4 yacc[4];
#pragma unroll
    for (int t = 0; t < 4; ++t) {
        const bf16x8 b = *(const bf16x8*)&wsm[OW1 + (t * 16 + ln) * SW1 + qd * 8];
        const float bv = bd1[t * 16 + ln];
        f32x4 acc = {bv, bv, bv, bv};
        yacc[t] = __builtin_amdgcn_mfma_f32_16x16x32_bf16(ax, b, acc, 0, 0, 0);
    }
#pragma unroll
    for (int t = 0; t < 4; ++t)
#pragma unroll
        for (int r = 0; r < 4; ++r)
            A[(qd * 4 + r) * SA + t * 16 + ln] = fmaxf(yacc[t][r], 0.f);   // fp32

    // ---- d2: D[16x16] = relu(Y) @ Wd2 (single bf16) ----
    {
        bf16x8 a0, a1;
#pragma unroll
        for (int j = 0; j < 8; ++j) a0[j] = (short)f2bf(A[ln * SA + qd * 8 + j]);
#pragma unroll
        for (int j = 0; j < 8; ++j) a1[j] = (short)f2bf(A[ln * SA + 32 + qd * 8 + j]);
        const bf16x8 b0 = *(const bf16x8*)&wsm[OW2 + ln * SW + qd * 8];
        const bf16x8 b1 = *(const bf16x8*)&wsm[OW2 + ln * SW + 32 + qd * 8];
        const float bv = bd2[ln];
        f32x4 acc = {bv, bv, bv, bv};
        acc = __builtin_amdgcn_mfma_f32_16x16x32_bf16(a0, b0, acc, 0, 0, 0);
        acc = __builtin_amdgcn_mfma_f32_16x16x32_bf16(a1, b1, acc, 0, 0, 0);
        if (ln == 15) {
#pragma unroll
            for (int r = 0; r < 4; ++r)
                out[3 * n + pt_base + qd * 4 + r] = fmaxf(acc[r], 0.f);    // sigma
        }
#pragma unroll
        for (int r = 0; r < 4; ++r)
            A[(qd * 4 + r) * SA + ln] = acc[r];        // raw D fp32, k=0..15
    }

    // ---- SH -> act fp32, k=16..40 (k=41..63 = stale relu(y), Wc1 rows 0) ----
    {
        const float dx = dirp[3 * pt + 0];
        const float dy = dirp[3 * pt + 1];
        const float dz = dirp[3 * pt + 2];
        float sh[25];
        SH_BLOCK(sh, dx, dy, dz)
        for (int i = qd; i < 25; i += 4)
            A[ln * SA + 16 + i] = sh[i];
    }

#define LOAD_SPLIT(ah, al, k0)                                   \
    {                                                            \
        _Pragma("unroll")                                        \
        for (int j = 0; j < 8; ++j) {                            \
            const float v = A[ln * SA + (k0) + j];               \
            const unsigned short hb = f2bf(v);                   \
            ah[j] = (short)hb;                                   \
            al[j] = (short)f2bf(v - b2f(hb));                    \
        }                                                        \
    }

#define SPLIT_TILE(acc, ah0, ah1, al0, al1, OH, OL, row)                                          \
    {                                                                                             \
        const bf16x8 bh0 = *(const bf16x8*)&wsm[(OH) + (row) * SW + qd * 8];                      \
        const bf16x8 bh1 = *(const bf16x8*)&wsm[(OH) + (row) * SW + 32 + qd * 8];                 \
        const bf16x8 bl0 = *(const bf16x8*)&wsm[(OL) + (row) * SW + qd * 8];                      \
        const bf16x8 bl1 = *(const bf16x8*)&wsm[(OL) + (row) * SW + 32 + qd * 8];                 \
        acc = __builtin_amdgcn_mfma_f32_16x16x32_bf16(ah0, bh0, acc, 0, 0, 0);                    \
        acc = __builtin_amdgcn_mfma_f32_16x16x32_bf16(ah1, bh1, acc, 0, 0, 0);                    \
        acc = __builtin_amdgcn_mfma_f32_16x16x32_bf16(al0, bh0, acc, 0, 0, 0);                    \
        acc = __builtin_amdgcn_mfma_f32_16x16x32_bf16(al1, bh1, acc, 0, 0, 0);                    \
        acc = __builtin_amdgcn_mfma_f32_16x16x32_bf16(ah0, bl0, acc, 0, 0, 0);                    \
        acc = __builtin_amdgcn_mfma_f32_16x16x32_bf16(ah1, bl1, acc, 0, 0, 0);                    \
    }

    // ---- c1: H1 = [D|SH|0] @ Wc1 (split) ----
    {
        bf16x8 ah0, ah1, al0, al1;
        LOAD_SPLIT(ah0, al0, qd * 8)
        LOAD_SPLIT(ah1, al1, 32 + qd * 8)
        f32x4 hacc[4];
#pragma unroll
        for (int t = 0; t < 4; ++t) {
            const float bv = bc1[t * 16 + ln];
            f32x4 acc = {bv, bv, bv, bv};
            SPLIT_TILE(acc, ah0, ah1, al0, al1, OC1H, OC1L, t * 16 + ln)
            hacc[t] = acc;
        }
#pragma unroll
        for (int t = 0; t < 4; ++t)
#pragma unroll
            for (int r = 0; r < 4; ++r)
                A[(qd * 4 + r) * SA + t * 16 + ln] = fmaxf(hacc[t][r], 0.f);
    }

    // ---- c2: H2 = relu(H1) @ Wc2 (split) ----
    {
        bf16x8 ah0, ah1, al0, al1;
        LOAD_SPLIT(ah0, al0, qd * 8)
        LOAD_SPLIT(ah1, al1, 32 + qd * 8)
        f32x4 hacc[4];
#pragma unroll
        for (int t = 0; t < 4; ++t) {
            const float bv = bc2[t * 16 + ln];
            f32x4 acc = {bv, bv, bv, bv};
            SPLIT_TILE(acc, ah0, ah1, al0, al1, OC2H, OC2L, t * 16 + ln)
            hacc[t] = acc;
        }
#pragma unroll
        for (int t = 0; t < 4; ++t)
#pragma unroll
            for (int r = 0; r < 4; ++r)
                A[(qd * 4 + r) * SA + t * 16 + ln] = fmaxf(hacc[t][r], 0.f);
    }

    // ---- c3 + sigmoid: R = relu(H2) @ Wc3 (split) ----
    {
        bf16x8 ah0, ah1, al0, al1;
        LOAD_SPLIT(ah0, al0, qd * 8)
        LOAD_SPLIT(ah1, al1, 32 + qd * 8)
        const float bv = (ln < 3) ? bc3[ln] : 0.f;
        f32x4 acc = {bv, bv, bv, bv};
        SPLIT_TILE(acc, ah0, ah1, al0, al1, OC3H, OC3L, ln)
        if (ln < 3) {
#pragma unroll
            for (int r = 0; r < 4; ++r)
                out[3 * (pt_base + qd * 4 + r) + ln] = 1.f / (1.f + expf(-acc[r]));
        }
    }
}

// ------------------------------------------------------------------
// Fallback: round-1 fused kernel (if ws too small / n not 2^19) — proven
// ------------------------------------------------------------------
__global__ __launch_bounds__(256)
void nerf_fused(const float* __restrict__ pos,
                const float* __restrict__ dirp,
                const float* __restrict__ tables,
                const float* __restrict__ Wd1, const float* __restrict__ bd1,
                const float* __restrict__ Wd2, const float* __restrict__ bd2,
                const float* __restrict__ Wc1, const float* __restrict__ bc1,
                const float* __restrict__ Wc2, const float* __restrict__ bc2,
                const float* __restrict__ Wc3, const float* __restrict__ bc3,
                float* __restrict__ out, int n)
{
    const int idx = blockIdx.x * blockDim.x + threadIdx.x;
    if (idx >= n) return;
    const float px = pos[3 * idx + 0], py = pos[3 * idx + 1], pz = pos[3 * idx + 2];
    float y[64];
#pragma unroll
    for (int j = 0; j < 64; ++j) y[j] = bd1[j];
#pragma unroll
    for (int l = 0; l < LEVELS; ++l) {
        const float resf = (float)(16 << l);
        const float tx = px * resf, ty = py * resf, tz = pz * resf;
        const float fx = floorf(tx), fy = floorf(ty), fz = floorf(tz);
        const float wx = tx - fx, wy = ty - fy, wz = tz - fz;
        const unsigned ix = (unsigned)(int)fx, iy = (unsigned)(int)fy, iz = (unsigned)(int)fz;
        const unsigned hy0 = iy * 2654435761u, hy1 = hy0 + 2654435761u;
        const unsigned hz0 = iz * 805459861u,  hz1 = hz0 + 805459861u;
        const unsigned ix1 = ix + 1u;
        const float2* tb = (const float2*)tables + (size_t)l * TBL;
        const float2 e000 = tb[(ix  ^ hy0 ^ hz0) & TMASK];
        const float2 e001 = tb[(ix  ^ hy0 ^ hz1) & TMASK];
        const float2 e010 = tb[(ix  ^ hy1 ^ hz0) & TMASK];
        const float2 e011 = tb[(ix  ^ hy1 ^ hz1) & TMASK];
        const float2 e100 = tb[(ix1 ^ hy0 ^ hz0) & TMASK];
        const float2 e101 = tb[(ix1 ^ hy0 ^ hz1) & TMASK];
        const float2 e110 = tb[(ix1 ^ hy1 ^ hz0) & TMASK];
        const float2 e111 = tb[(ix1 ^ hy1 ^ hz1) & TMASK];
        const float ux = 1.f - wx, uy = 1.f - wy, uz = 1.f - wz;
        const float c000 = ux*uy*uz, c001 = ux*uy*wz, c010 = ux*wy*uz, c011 = ux*wy*wz;
        const float c100 = wx*uy*uz, c101 = wx*uy*wz, c110 = wx*wy*uz, c111 = wx*wy*wz;
        float f0 = e000.x*c000, f1 = e000.y*c000;
        f0 = fmaf(e001.x,c001,f0); f1 = fmaf(e001.y,c001,f1);
        f0 = fmaf(e010.x,c010,f0); f1 = fmaf(e010.y,c010,f1);
        f0 = fmaf(e011.x,c011,f0); f1 = fmaf(e011.y,c011,f1);
        f0 = fmaf(e100.x,c100,f0); f1 = fmaf(e100.y,c100,f1);
        f0 = fmaf(e101.x,c101,f0); f1 = fmaf(e101.y,c101,f1);
        f0 = fmaf(e110.x,c110,f0); f1 = fmaf(e110.y,c110,f1);
        f0 = fmaf(e111.x,c111,f0); f1 = fmaf(e111.y,c111,f1);
        const float* w0 = Wd1 + (size_t)(2 * l) * 64;
#pragma unroll
        for (int j = 0; j < 64; ++j)
            y[j] = fmaf(f0, w0[j], fmaf(f1, w0[64 + j], y[j]));
    }
    float d[16];
#pragma unroll
    for (int k = 0; k < 16; ++k) d[k] = bd2[k];
#pragma unroll
    for (int j = 0; j < 64; ++j) {
        const float a = fmaxf(y[j], 0.f);
#pragma unroll
        for (int k = 0; k < 16; ++k) d[k] = fmaf(a, Wd2[j * 16 + k], d[k]);
    }
    out[3 * n + idx] = fmaxf(d[15], 0.f);
    const float dx = dirp[3*idx], dy = dirp[3*idx+1], dz = dirp[3*idx+2];
    float sh[25];
    SH_BLOCK(sh, dx, dy, dz)
    float h1[64];
#pragma unroll
    for (int j = 0; j < 64; ++j) h1[j] = bc1[j];
#pragma unroll
    for (int i = 0; i < 16; ++i) {
#pragma unroll
        for (int j = 0; j < 64; ++j) h1[j] = fmaf(d[i], Wc1[i * 64 + j], h1[j]);
    }
#pragma unroll
    for (int s = 0; s < 25; ++s) {
#pragma unroll
        for (int j = 0; j < 64; ++j) h1[j] = fmaf(sh[s], Wc1[(16 + s) * 64 + j], h1[j]);
    }
    float h2[64];
#pragma unroll
    for (int j = 0; j < 64; ++j) h2[j] = bc2[j];
#pragma unroll
    for (int i = 0; i < 64; ++i) {
        const float a = fmaxf(h1[i], 0.f);
#pragma unroll
        for (int j = 0; j < 64; ++j) h2[j] = fmaf(a, Wc2[i * 64 + j], h2[j]);
    }
    float r0 = bc3[0], r1 = bc3[1], r2 = bc3[2];
#pragma unroll
    for (int j = 0; j < 64; ++j) {
        const float a = fmaxf(h2[j], 0.f);
        r0 = fmaf(a, Wc3[j * 3 + 0], r0);
        r1 = fmaf(a, Wc3[j * 3 + 1], r1);
        r2 = fmaf(a, Wc3[j * 3 + 2], r2);
    }
    out[3 * idx + 0] = 1.f / (1.f + expf(-r0));
    out[3 * idx + 1] = 1.f / (1.f + expf(-r1));
    out[3 * idx + 2] = 1.f / (1.f + expf(-r2));
}

extern "C" void kernel_launch(void* const* d_in, const int* in_sizes, int n_in,
                              void* d_out, int out_size, void* d_ws, size_t ws_size,
                              hipStream_t stream) {
    const float* pos    = (const float*)d_in[0];
    const float* dir    = (const float*)d_in[1];
    const float* tables = (const float*)d_in[2];
    const float* Wd1 = (const float*)d_in[3];
    const float* bd1 = (const float*)d_in[4];
    const float* Wd2 = (const float*)d_in[5];
    const float* bd2 = (const float*)d_in[6];
    const float* Wc1 = (const float*)d_in[7];
    const float* bc1 = (const float*)d_in[8];
    const float* Wc2 = (const float*)d_in[9];
    const float* bc2 = (const float*)d_in[10];
    const float* Wc3 = (const float*)d_in[11];
    const float* bc3 = (const float*)d_in[12];

    const int n = in_sizes[0] / 3;
    const int blocks = (n + 255) / 256;
    const size_t need = (size_t)n * 128;   // 16 float2 planes = 32 floats/point

    if (ws_size >= need && n == 524288) {
        ngp_encode_lvl<<<16 * blocks, 256, 0, stream>>>(pos, tables, (float2*)d_ws, n);
        ngp_mlp_mfma2<<<n / 64, 256, 0, stream>>>((const float2*)d_ws, dir,
                                                  Wd1, bd1, Wd2, bd2,
                                                  Wc1, bc1, Wc2, bc2, Wc3, bc3,
                                                  (float*)d_out, n);
    } else {
        nerf_fused<<<blocks, 256, 0, stream>>>(pos, dir, tables,
                                               Wd1, bd1, Wd2, bd2,
                                               Wc1, bc1, Wc2, bc2, Wc3, bc3,
                                               (float*)d_out, n);
    }
}

// Round 9
// 513.187 us; speedup vs baseline: 1.1767x; 1.1767x over previous
//
#include <hip/hip_runtime.h>
#include <math.h>

#define LEVELS 16
#define TBL 524288          // 2^19 entries per level
#define TMASK (TBL - 1)

typedef short bf16x8 __attribute__((ext_vector_type(8)));
typedef float f32x4  __attribute__((ext_vector_type(4)));

static __device__ __forceinline__ unsigned short f2bf(float x) {
    unsigned u = __float_as_uint(x);
    u += 0x7fffu + ((u >> 16) & 1u);    // RNE
    return (unsigned short)(u >> 16);
}
static __device__ __forceinline__ float b2f(unsigned short h) {
    return __uint_as_float(((unsigned)h) << 16);
}

// SH degree-4 block, constants computed exactly as round-1 (verified correct).
#define SH_BLOCK(sh, dx, dy, dz)                                                          \
    const float x2 = dx * dx, y2 = dy * dy, z2 = dz * dz;                                 \
    const float xy = dx * dy, xz = dx * dz, yz = dy * dz;                                 \
    const float x4 = x2 * x2, y4 = y2 * y2;                                               \
    const float c0  = (float)(0.5 * sqrt(1.0 / M_PI));                                    \
    const float c1  = (float)(0.5 * sqrt(3.0 / M_PI));                                    \
    const float sub = (float)(0.25 * sqrt(5.0 / M_PI));                                   \
    const float v1  = (float)(0.25 * sqrt(15.0 / M_PI));                                  \
    const float v2  = (float)(0.5 * sqrt(15.0 / M_PI));                                   \
    const float v3  = (float)(0.75 * sqrt(5.0 / M_PI));                                   \
    const float w1c = (float)(0.25 * sqrt(105.0 / M_PI));                                 \
    const float w2c = (float)(0.5 * sqrt(105.0 / M_PI));                                  \
    const float w3c = (float)(0.25 * sqrt(35.0 / (2.0 * M_PI)));                          \
    const float w4c = (float)(0.5 * sqrt(7.0 / (6.0 * M_PI)));                            \
    sh[0] = c0;                                                                           \
    sh[1] = -c1 * dy;                                                                     \
    sh[2] =  c1 * dz;                                                                     \
    sh[3] = -c1 * dx;                                                                     \
    sh[4] =  v2 * xy;                                                                     \
    sh[5] = -v2 * yz;                                                                     \
    sh[6] =  v3 * z2 - sub;                                                               \
    sh[7] = -v2 * xz;                                                                     \
    sh[8] =  v1 * x2 - v1 * y2;                                                           \
    sh[9]  = -w3c * dy * (3.0f * x2 - y2);                                                \
    sh[10] =  w2c * xy * dz;                                                              \
    sh[11] =  w4c * dy * (1.5f - 7.5f * z2);                                              \
    sh[12] =  1.24392110863372f * dz * (1.5f * z2 - 0.5f) - 0.497568443453487f * dz;      \
    sh[13] =  w4c * dx * (1.5f - 7.5f * z2);                                              \
    sh[14] =  w1c * dz * (x2 - y2);                                                       \
    sh[15] = -w3c * dx * (x2 - 3.0f * y2);                                                \
    sh[16] =  2.5033429417967f * xy * (x2 - y2);                                          \
    sh[17] = -1.77013076977993f * yz * (3.0f * x2 - y2);                                  \
    sh[18] =  0.126156626101008f * xy * (52.5f * z2 - 7.5f);                              \
    sh[19] =  0.267618617422916f * dy * (2.33333333333333f * dz * (1.5f - 7.5f * z2) + 4.0f * dz); \
    sh[20] =  1.48099765681286f * dz * (1.66666666666667f * dz * (1.5f * z2 - 0.5f) - 0.666666666666667f * dz) \
              - 0.952069922236839f * z2 + 0.317356640745613f;                             \
    sh[21] =  0.267618617422916f * dx * (2.33333333333333f * dz * (1.5f - 7.5f * z2) + 4.0f * dz); \
    sh[22] =  0.063078313050504f * (x2 - y2) * (52.5f * z2 - 7.5f);                       \
    sh[23] = -1.77013076977993f * xz * (x2 - 3.0f * y2);                                  \
    sh[24] = -3.75501441269506f * x2 * y2 + 0.625835735449176f * x4 + 0.625835735449176f * y4;

// ------------------------------------------------------------------
// Kernel 1: hash-grid gather with level<->XCD affinity (unchanged R6).
// ------------------------------------------------------------------
__global__ __launch_bounds__(256)
void ngp_encode_lvl(const float* __restrict__ pos,
                    const float* __restrict__ tables,
                    float2* __restrict__ ws2, int n)
{
    const int b = blockIdx.x;
    const int p = b & 7;
    const int h = b >> 14;                 // 16384 blocks per half (n = 2^19)
    const int l = 2 * p + h;
    const int c = (b & 16383) >> 3;
    const int idx = c * 256 + threadIdx.x;
    if (idx >= n || l >= LEVELS) return;

    const float px = pos[3 * idx + 0];
    const float py = pos[3 * idx + 1];
    const float pz = pos[3 * idx + 2];

    const float resf = (float)(16 << l);
    const float tx = px * resf, ty = py * resf, tz = pz * resf;
    const float fx = floorf(tx), fy = floorf(ty), fz = floorf(tz);
    const float wx = tx - fx, wy = ty - fy, wz = tz - fz;
    const unsigned ix = (unsigned)(int)fx;
    const unsigned iy = (unsigned)(int)fy;
    const unsigned iz = (unsigned)(int)fz;
    const unsigned hy0 = iy * 2654435761u, hy1 = hy0 + 2654435761u;
    const unsigned hz0 = iz * 805459861u,  hz1 = hz0 + 805459861u;
    const unsigned ix1 = ix + 1u;

    const float2* tb = (const float2*)tables + (size_t)l * TBL;
    const float2 e000 = tb[(ix  ^ hy0 ^ hz0) & TMASK];
    const float2 e001 = tb[(ix  ^ hy0 ^ hz1) & TMASK];
    const float2 e010 = tb[(ix  ^ hy1 ^ hz0) & TMASK];
    const float2 e011 = tb[(ix  ^ hy1 ^ hz1) & TMASK];
    const float2 e100 = tb[(ix1 ^ hy0 ^ hz0) & TMASK];
    const float2 e101 = tb[(ix1 ^ hy0 ^ hz1) & TMASK];
    const float2 e110 = tb[(ix1 ^ hy1 ^ hz0) & TMASK];
    const float2 e111 = tb[(ix1 ^ hy1 ^ hz1) & TMASK];

    const float ux = 1.f - wx, uy = 1.f - wy, uz = 1.f - wz;
    const float c000 = ux * uy * uz, c001 = ux * uy * wz;
    const float c010 = ux * wy * uz, c011 = ux * wy * wz;
    const float c100 = wx * uy * uz, c101 = wx * uy * wz;
    const float c110 = wx * wy * uz, c111 = wx * wy * wz;

    float f0 = e000.x * c000, f1 = e000.y * c000;
    f0 = fmaf(e001.x, c001, f0); f1 = fmaf(e001.y, c001, f1);
    f0 = fmaf(e010.x, c010, f0); f1 = fmaf(e010.y, c010, f1);
    f0 = fmaf(e011.x, c011, f0); f1 = fmaf(e011.y, c011, f1);
    f0 = fmaf(e100.x, c100, f0); f1 = fmaf(e100.y, c100, f1);
    f0 = fmaf(e101.x, c101, f0); f1 = fmaf(e101.y, c101, f1);
    f0 = fmaf(e110.x, c110, f0); f1 = fmaf(e110.y, c110, f1);
    f0 = fmaf(e111.x, c111, f0); f1 = fmaf(e111.y, c111, f1);

    ws2[(size_t)l * n + idx] = make_float2(f0, f1);
}

// ------------------------------------------------------------------
// Kernel 2: split-precision MFMA MLP, persistent blocks.
// Grid = 1024 blocks; each block stages weights ONCE, then loops
// GROUPS=8 point-groups of 64 (4 waves x 16 points each).
// Inner pipeline identical to R8 (proven correct, absmax 3.9e-3).
// ------------------------------------------------------------------
#define MT   256
#define GROUPS 8
#define SW1  32                  // Wd1 k-stride (shorts), rows 16B-aligned
#define SW   72                  // 64-k weight stride (shorts), rows 16B-aligned
#define SA   66                  // act k-stride (floats)
#define OW1  0                   // 64*32 = 2048
#define OW2  2048                // 16*72 = 1152
#define OC1H 3200                // 64*72 = 4608
#define OC1L 7808
#define OC2H 12416
#define OC2L 17024
#define OC3H 21632               // 16*72 = 1152
#define OC3L 22784
#define WTOT 23936               // shorts = 47872 B; + act 16896 B = 64768 B

__global__ __launch_bounds__(256, 2)
void ngp_mlp_mfma3(const float2* __restrict__ ws2,
                   const float* __restrict__ dirp,
                   const float* __restrict__ Wd1, const float* __restrict__ bd1,
                   const float* __restrict__ Wd2, const float* __restrict__ bd2,
                   const float* __restrict__ Wc1, const float* __restrict__ bc1,
                   const float* __restrict__ Wc2, const float* __restrict__ bc2,
                   const float* __restrict__ Wc3, const float* __restrict__ bc3,
                   float* __restrict__ out, int n)
{
    __shared__ short wsm[WTOT];
    __shared__ float act[4 * 16 * SA];
    const int tid = threadIdx.x;

    for (int t = tid; t < WTOT; t += MT) wsm[t] = 0;
    __syncthreads();

    for (int g = tid; g < 32 * 64; g += MT) {            // Wd1 (32,64) single
        const int k = g >> 6, nn = g & 63;
        wsm[OW1 + nn * SW1 + k] = f2bf(Wd1[g]);
    }
    for (int g = tid; g < 64 * 16; g += MT) {            // Wd2 (64,16) single
        const int k = g >> 4, nn = g & 15;
        wsm[OW2 + nn * SW + k] = f2bf(Wd2[g]);
    }
    for (int g = tid; g < 41 * 64; g += MT) {            // Wc1 (41,64) hi+lo
        const int k = g >> 6, nn = g & 63;
        const float w = Wc1[g];
        const unsigned short hh = f2bf(w);
        wsm[OC1H + nn * SW + k] = hh;
        wsm[OC1L + nn * SW + k] = f2bf(w - b2f(hh));
    }
    for (int g = tid; g < 64 * 64; g += MT) {            // Wc2 (64,64) hi+lo
        const int k = g >> 6, nn = g & 63;
        const float w = Wc2[g];
        const unsigned short hh = f2bf(w);
        wsm[OC2H + nn * SW + k] = hh;
        wsm[OC2L + nn * SW + k] = f2bf(w - b2f(hh));
    }
    for (int g = tid; g < 64 * 3; g += MT) {             // Wc3 (64,3) hi+lo
        const int k = g / 3, nn = g - 3 * k;
        const float w = Wc3[g];
        const unsigned short hh = f2bf(w);
        wsm[OC3H + nn * SW + k] = hh;
        wsm[OC3L + nn * SW + k] = f2bf(w - b2f(hh));
    }
    __syncthreads();

    const int wid = tid >> 6;
    const int lane = tid & 63;
    const int ln = lane & 15;
    const int qd = lane >> 4;
    float* A = act + wid * (16 * SA);

#define LOAD_SPLIT(ah, al, k0)                                   \
    {                                                            \
        _Pragma("unroll")                                        \
        for (int j = 0; j < 8; ++j) {                            \
            const float v = A[ln * SA + (k0) + j];               \
            const unsigned short hb = f2bf(v);                   \
            ah[j] = (short)hb;                                   \
            al[j] = (short)f2bf(v - b2f(hb));                    \
        }                                                        \
    }

#define SPLIT_TILE(acc, ah0, ah1, al0, al1, OH, OL, row)                                          \
    {                                                                                             \
        const bf16x8 bh0 = *(const bf16x8*)&wsm[(OH) + (row) * SW + qd * 8];                      \
        const bf16x8 bh1 = *(const bf16x8*)&wsm[(OH) + (row) * SW + 32 + qd * 8];                 \
        const bf16x8 bl0 = *(const bf16x8*)&wsm[(OL) + (row) * SW + qd * 8];                      \
        const bf16x8 bl1 = *(const bf16x8*)&wsm[(OL) + (row) * SW + 32 + qd * 8];                 \
        acc = __builtin_amdgcn_mfma_f32_16x16x32_bf16(ah0, bh0, acc, 0, 0, 0);                    \
        acc = __builtin_amdgcn_mfma_f32_16x16x32_bf16(ah1, bh1, acc, 0, 0, 0);                    \
        acc = __builtin_amdgcn_mfma_f32_16x16x32_bf16(al0, bh0, acc, 0, 0, 0);                    \
        acc = __builtin_amdgcn_mfma_f32_16x16x32_bf16(al1, bh1, acc, 0, 0, 0);                    \
        acc = __builtin_amdgcn_mfma_f32_16x16x32_bf16(ah0, bl0, acc, 0, 0, 0);                    \
        acc = __builtin_amdgcn_mfma_f32_16x16x32_bf16(ah1, bl1, acc, 0, 0, 0);                    \
    }

    for (int grp = 0; grp < GROUPS; ++grp) {
        const int pt_base = (blockIdx.x * GROUPS + grp) * 64 + wid * 16;
        const int pt = pt_base + ln;

        // ---- d1: Y[16x64] = X @ Wd1 (single bf16) ----
        bf16x8 ax;
#pragma unroll
        for (int s = 0; s < 4; ++s) {
            const float2 q = ws2[(size_t)(qd * 4 + s) * n + pt];
            ax[2 * s + 0] = (short)f2bf(q.x);
            ax[2 * s + 1] = (short)f2bf(q.y);
        }
        f32x4 yacc[4];
#pragma unroll
        for (int t = 0; t < 4; ++t) {
            const bf16x8 b = *(const bf16x8*)&wsm[OW1 + (t * 16 + ln) * SW1 + qd * 8];
            const float bv = bd1[t * 16 + ln];
            f32x4 acc = {bv, bv, bv, bv};
            yacc[t] = __builtin_amdgcn_mfma_f32_16x16x32_bf16(ax, b, acc, 0, 0, 0);
        }
#pragma unroll
        for (int t = 0; t < 4; ++t)
#pragma unroll
            for (int r = 0; r < 4; ++r)
                A[(qd * 4 + r) * SA + t * 16 + ln] = fmaxf(yacc[t][r], 0.f);   // fp32

        // ---- d2: D[16x16] = relu(Y) @ Wd2 (single bf16) ----
        {
            bf16x8 a0, a1;
#pragma unroll
            for (int j = 0; j < 8; ++j) a0[j] = (short)f2bf(A[ln * SA + qd * 8 + j]);
#pragma unroll
            for (int j = 0; j < 8; ++j) a1[j] = (short)f2bf(A[ln * SA + 32 + qd * 8 + j]);
            const bf16x8 b0 = *(const bf16x8*)&wsm[OW2 + ln * SW + qd * 8];
            const bf16x8 b1 = *(const bf16x8*)&wsm[OW2 + ln * SW + 32 + qd * 8];
            const float bv = bd2[ln];
            f32x4 acc = {bv, bv, bv, bv};
            acc = __builtin_amdgcn_mfma_f32_16x16x32_bf16(a0, b0, acc, 0, 0, 0);
            acc = __builtin_amdgcn_mfma_f32_16x16x32_bf16(a1, b1, acc, 0, 0, 0);
            if (ln == 15) {
#pragma unroll
                for (int r = 0; r < 4; ++r)
                    out[3 * n + pt_base + qd * 4 + r] = fmaxf(acc[r], 0.f);    // sigma
            }
#pragma unroll
            for (int r = 0; r < 4; ++r)
                A[(qd * 4 + r) * SA + ln] = acc[r];        // raw D fp32, k=0..15
        }

        // ---- SH -> act fp32, k=16..40 (k=41..63 stale, Wc1 rows zeroed) ----
        {
            const float dx = dirp[3 * pt + 0];
            const float dy = dirp[3 * pt + 1];
            const float dz = dirp[3 * pt + 2];
            float sh[25];
            SH_BLOCK(sh, dx, dy, dz)
            for (int i = qd; i < 25; i += 4)
                A[ln * SA + 16 + i] = sh[i];
        }

        // ---- c1: H1 = [D|SH|0] @ Wc1 (split) ----
        {
            bf16x8 ah0, ah1, al0, al1;
            LOAD_SPLIT(ah0, al0, qd * 8)
            LOAD_SPLIT(ah1, al1, 32 + qd * 8)
            f32x4 hacc[4];
#pragma unroll
            for (int t = 0; t < 4; ++t) {
                const float bv = bc1[t * 16 + ln];
                f32x4 acc = {bv, bv, bv, bv};
                SPLIT_TILE(acc, ah0, ah1, al0, al1, OC1H, OC1L, t * 16 + ln)
                hacc[t] = acc;
            }
#pragma unroll
            for (int t = 0; t < 4; ++t)
#pragma unroll
                for (int r = 0; r < 4; ++r)
                    A[(qd * 4 + r) * SA + t * 16 + ln] = fmaxf(hacc[t][r], 0.f);
        }

        // ---- c2: H2 = relu(H1) @ Wc2 (split) ----
        {
            bf16x8 ah0, ah1, al0, al1;
            LOAD_SPLIT(ah0, al0, qd * 8)
            LOAD_SPLIT(ah1, al1, 32 + qd * 8)
            f32x4 hacc[4];
#pragma unroll
            for (int t = 0; t < 4; ++t) {
                const float bv = bc2[t * 16 + ln];
                f32x4 acc = {bv, bv, bv, bv};
                SPLIT_TILE(acc, ah0, ah1, al0, al1, OC2H, OC2L, t * 16 + ln)
                hacc[t] = acc;
            }
#pragma unroll
            for (int t = 0; t < 4; ++t)
#pragma unroll
                for (int r = 0; r < 4; ++r)
                    A[(qd * 4 + r) * SA + t * 16 + ln] = fmaxf(hacc[t][r], 0.f);
        }

        // ---- c3 + sigmoid: R = relu(H2) @ Wc3 (split) ----
        {
            bf16x8 ah0, ah1, al0, al1;
            LOAD_SPLIT(ah0, al0, qd * 8)
            LOAD_SPLIT(ah1, al1, 32 + qd * 8)
            const float bv = (ln < 3) ? bc3[ln] : 0.f;
            f32x4 acc = {bv, bv, bv, bv};
            SPLIT_TILE(acc, ah0, ah1, al0, al1, OC3H, OC3L, ln)
            if (ln < 3) {
#pragma unroll
                for (int r = 0; r < 4; ++r)
                    out[3 * (pt_base + qd * 4 + r) + ln] = 1.f / (1.f + expf(-acc[r]));
            }
        }
    }
}

// ------------------------------------------------------------------
// Fallback: round-1 fused kernel (if ws too small / n not 2^19) — proven
// ------------------------------------------------------------------
__global__ __launch_bounds__(256)
void nerf_fused(const float* __restrict__ pos,
                const float* __restrict__ dirp,
                const float* __restrict__ tables,
                const float* __restrict__ Wd1, const float* __restrict__ bd1,
                const float* __restrict__ Wd2, const float* __restrict__ bd2,
                const float* __restrict__ Wc1, const float* __restrict__ bc1,
                const float* __restrict__ Wc2, const float* __restrict__ bc2,
                const float* __restrict__ Wc3, const float* __restrict__ bc3,
                float* __restrict__ out, int n)
{
    const int idx = blockIdx.x * blockDim.x + threadIdx.x;
    if (idx >= n) return;
    const float px = pos[3 * idx + 0], py = pos[3 * idx + 1], pz = pos[3 * idx + 2];
    float y[64];
#pragma unroll
    for (int j = 0; j < 64; ++j) y[j] = bd1[j];
#pragma unroll
    for (int l = 0; l < LEVELS; ++l) {
        const float resf = (float)(16 << l);
        const float tx = px * resf, ty = py * resf, tz = pz * resf;
        const float fx = floorf(tx), fy = floorf(ty), fz = floorf(tz);
        const float wx = tx - fx, wy = ty - fy, wz = tz - fz;
        const unsigned ix = (unsigned)(int)fx, iy = (unsigned)(int)fy, iz = (unsigned)(int)fz;
        const unsigned hy0 = iy * 2654435761u, hy1 = hy0 + 2654435761u;
        const unsigned hz0 = iz * 805459861u,  hz1 = hz0 + 805459861u;
        const unsigned ix1 = ix + 1u;
        const float2* tb = (const float2*)tables + (size_t)l * TBL;
        const float2 e000 = tb[(ix  ^ hy0 ^ hz0) & TMASK];
        const float2 e001 = tb[(ix  ^ hy0 ^ hz1) & TMASK];
        const float2 e010 = tb[(ix  ^ hy1 ^ hz0) & TMASK];
        const float2 e011 = tb[(ix  ^ hy1 ^ hz1) & TMASK];
        const float2 e100 = tb[(ix1 ^ hy0 ^ hz0) & TMASK];
        const float2 e101 = tb[(ix1 ^ hy0 ^ hz1) & TMASK];
        const float2 e110 = tb[(ix1 ^ hy1 ^ hz0) & TMASK];
        const float2 e111 = tb[(ix1 ^ hy1 ^ hz1) & TMASK];
        const float ux = 1.f - wx, uy = 1.f - wy, uz = 1.f - wz;
        const float c000 = ux*uy*uz, c001 = ux*uy*wz, c010 = ux*wy*uz, c011 = ux*wy*wz;
        const float c100 = wx*uy*uz, c101 = wx*uy*wz, c110 = wx*wy*uz, c111 = wx*wy*wz;
        float f0 = e000.x*c000, f1 = e000.y*c000;
        f0 = fmaf(e001.x,c001,f0); f1 = fmaf(e001.y,c001,f1);
        f0 = fmaf(e010.x,c010,f0); f1 = fmaf(e010.y,c010,f1);
        f0 = fmaf(e011.x,c011,f0); f1 = fmaf(e011.y,c011,f1);
        f0 = fmaf(e100.x,c100,f0); f1 = fmaf(e100.y,c100,f1);
        f0 = fmaf(e101.x,c101,f0); f1 = fmaf(e101.y,c101,f1);
        f0 = fmaf(e110.x,c110,f0); f1 = fmaf(e110.y,c110,f1);
        f0 = fmaf(e111.x,c111,f0); f1 = fmaf(e111.y,c111,f1);
        const float* w0 = Wd1 + (size_t)(2 * l) * 64;
#pragma unroll
        for (int j = 0; j < 64; ++j)
            y[j] = fmaf(f0, w0[j], fmaf(f1, w0[64 + j], y[j]));
    }
    float d[16];
#pragma unroll
    for (int k = 0; k < 16; ++k) d[k] = bd2[k];
#pragma unroll
    for (int j = 0; j < 64; ++j) {
        const float a = fmaxf(y[j], 0.f);
#pragma unroll
        for (int k = 0; k < 16; ++k) d[k] = fmaf(a, Wd2[j * 16 + k], d[k]);
    }
    out[3 * n + idx] = fmaxf(d[15], 0.f);
    const float dx = dirp[3*idx], dy = dirp[3*idx+1], dz = dirp[3*idx+2];
    float sh[25];
    SH_BLOCK(sh, dx, dy, dz)
    float h1[64];
#pragma unroll
    for (int j = 0; j < 64; ++j) h1[j] = bc1[j];
#pragma unroll
    for (int i = 0; i < 16; ++i) {
#pragma unroll
        for (int j = 0; j < 64; ++j) h1[j] = fmaf(d[i], Wc1[i * 64 + j], h1[j]);
    }
#pragma unroll
    for (int s = 0; s < 25; ++s) {
#pragma unroll
        for (int j = 0; j < 64; ++j) h1[j] = fmaf(sh[s], Wc1[(16 + s) * 64 + j], h1[j]);
    }
    float h2[64];
#pragma unroll
    for (int j = 0; j < 64; ++j) h2[j] = bc2[j];
#pragma unroll
    for (int i = 0; i < 64; ++i) {
        const float a = fmaxf(h1[i], 0.f);
#pragma unroll
        for (int j = 0; j < 64; ++j) h2[j] = fmaf(a, Wc2[i * 64 + j], h2[j]);
    }
    float r0 = bc3[0], r1 = bc3[1], r2 = bc3[2];
#pragma unroll
    for (int j = 0; j < 64; ++j) {
        const float a = fmaxf(h2[j], 0.f);
        r0 = fmaf(a, Wc3[j * 3 + 0], r0);
        r1 = fmaf(a, Wc3[j * 3 + 1], r1);
        r2 = fmaf(a, Wc3[j * 3 + 2], r2);
    }
    out[3 * idx + 0] = 1.f / (1.f + expf(-r0));
    out[3 * idx + 1] = 1.f / (1.f + expf(-r1));
    out[3 * idx + 2] = 1.f / (1.f + expf(-r2));
}

extern "C" void kernel_launch(void* const* d_in, const int* in_sizes, int n_in,
                              void* d_out, int out_size, void* d_ws, size_t ws_size,
                              hipStream_t stream) {
    const float* pos    = (const float*)d_in[0];
    const float* dir    = (const float*)d_in[1];
    const float* tables = (const float*)d_in[2];
    const float* Wd1 = (const float*)d_in[3];
    const float* bd1 = (const float*)d_in[4];
    const float* Wd2 = (const float*)d_in[5];
    const float* bd2 = (const float*)d_in[6];
    const float* Wc1 = (const float*)d_in[7];
    const float* bc1 = (const float*)d_in[8];
    const float* Wc2 = (const float*)d_in[9];
    const float* bc2 = (const float*)d_in[10];
    const float* Wc3 = (const float*)d_in[11];
    const float* bc3 = (const float*)d_in[12];

    const int n = in_sizes[0] / 3;
    const int blocks = (n + 255) / 256;
    const size_t need = (size_t)n * 128;   // 16 float2 planes = 32 floats/point

    if (ws_size >= need && n == 524288) {
        ngp_encode_lvl<<<16 * blocks, 256, 0, stream>>>(pos, tables, (float2*)d_ws, n);
        ngp_mlp_mfma3<<<n / (64 * GROUPS), 256, 0, stream>>>((const float2*)d_ws, dir,
                                                             Wd1, bd1, Wd2, bd2,
                                                             Wc1, bc1, Wc2, bc2, Wc3, bc3,
                                                             (float*)d_out, n);
    } else {
        nerf_fused<<<blocks, 256, 0, stream>>>(pos, dir, tables,
                                               Wd1, bd1, Wd2, bd2,
                                               Wc1, bc1, Wc2, bc2, Wc3, bc3,
                                               (float*)d_out, n);
    }
}

// Round 10
// 500.502 us; speedup vs baseline: 1.2066x; 1.0253x over previous
//
#include <hip/hip_runtime.h>
#include <math.h>

#define LEVELS 16
#define TBL 524288          // 2^19 entries per level
#define TMASK (TBL - 1)

typedef short bf16x8 __attribute__((ext_vector_type(8)));
typedef float f32x4  __attribute__((ext_vector_type(4)));

static __device__ __forceinline__ unsigned short f2bf(float x) {
    unsigned u = __float_as_uint(x);
    u += 0x7fffu + ((u >> 16) & 1u);    // RNE
    return (unsigned short)(u >> 16);
}
static __device__ __forceinline__ float b2f(unsigned short h) {
    return __uint_as_float(((unsigned)h) << 16);
}

// SH degree-4 block, constants computed exactly as round-1 (verified correct).
#define SH_BLOCK(sh, dx, dy, dz)                                                          \
    const float x2 = dx * dx, y2 = dy * dy, z2 = dz * dz;                                 \
    const float xy = dx * dy, xz = dx * dz, yz = dy * dz;                                 \
    const float x4 = x2 * x2, y4 = y2 * y2;                                               \
    const float c0  = (float)(0.5 * sqrt(1.0 / M_PI));                                    \
    const float c1  = (float)(0.5 * sqrt(3.0 / M_PI));                                    \
    const float sub = (float)(0.25 * sqrt(5.0 / M_PI));                                   \
    const float v1  = (float)(0.25 * sqrt(15.0 / M_PI));                                  \
    const float v2  = (float)(0.5 * sqrt(15.0 / M_PI));                                   \
    const float v3  = (float)(0.75 * sqrt(5.0 / M_PI));                                   \
    const float w1c = (float)(0.25 * sqrt(105.0 / M_PI));                                 \
    const float w2c = (float)(0.5 * sqrt(105.0 / M_PI));                                  \
    const float w3c = (float)(0.25 * sqrt(35.0 / (2.0 * M_PI)));                          \
    const float w4c = (float)(0.5 * sqrt(7.0 / (6.0 * M_PI)));                            \
    sh[0] = c0;                                                                           \
    sh[1] = -c1 * dy;                                                                     \
    sh[2] =  c1 * dz;                                                                     \
    sh[3] = -c1 * dx;                                                                     \
    sh[4] =  v2 * xy;                                                                     \
    sh[5] = -v2 * yz;                                                                     \
    sh[6] =  v3 * z2 - sub;                                                               \
    sh[7] = -v2 * xz;                                                                     \
    sh[8] =  v1 * x2 - v1 * y2;                                                           \
    sh[9]  = -w3c * dy * (3.0f * x2 - y2);                                                \
    sh[10] =  w2c * xy * dz;                                                              \
    sh[11] =  w4c * dy * (1.5f - 7.5f * z2);                                              \
    sh[12] =  1.24392110863372f * dz * (1.5f * z2 - 0.5f) - 0.497568443453487f * dz;      \
    sh[13] =  w4c * dx * (1.5f - 7.5f * z2);                                              \
    sh[14] =  w1c * dz * (x2 - y2);                                                       \
    sh[15] = -w3c * dx * (x2 - 3.0f * y2);                                                \
    sh[16] =  2.5033429417967f * xy * (x2 - y2);                                          \
    sh[17] = -1.77013076977993f * yz * (3.0f * x2 - y2);                                  \
    sh[18] =  0.126156626101008f * xy * (52.5f * z2 - 7.5f);                              \
    sh[19] =  0.267618617422916f * dy * (2.33333333333333f * dz * (1.5f - 7.5f * z2) + 4.0f * dz); \
    sh[20] =  1.48099765681286f * dz * (1.66666666666667f * dz * (1.5f * z2 - 0.5f) - 0.666666666666667f * dz) \
              - 0.952069922236839f * z2 + 0.317356640745613f;                             \
    sh[21] =  0.267618617422916f * dx * (2.33333333333333f * dz * (1.5f - 7.5f * z2) + 4.0f * dz); \
    sh[22] =  0.063078313050504f * (x2 - y2) * (52.5f * z2 - 7.5f);                       \
    sh[23] = -1.77013076977993f * xz * (x2 - 3.0f * y2);                                  \
    sh[24] = -3.75501441269506f * x2 * y2 + 0.625835735449176f * x4 + 0.625835735449176f * y4;

// ------------------------------------------------------------------
// Kernel 1: hash-grid gather with level<->XCD affinity (unchanged R6).
// ------------------------------------------------------------------
__global__ __launch_bounds__(256)
void ngp_encode_lvl(const float* __restrict__ pos,
                    const float* __restrict__ tables,
                    float2* __restrict__ ws2, int n)
{
    const int b = blockIdx.x;
    const int p = b & 7;
    const int h = b >> 14;                 // 16384 blocks per half (n = 2^19)
    const int l = 2 * p + h;
    const int c = (b & 16383) >> 3;
    const int idx = c * 256 + threadIdx.x;
    if (idx >= n || l >= LEVELS) return;

    const float px = pos[3 * idx + 0];
    const float py = pos[3 * idx + 1];
    const float pz = pos[3 * idx + 2];

    const float resf = (float)(16 << l);
    const float tx = px * resf, ty = py * resf, tz = pz * resf;
    const float fx = floorf(tx), fy = floorf(ty), fz = floorf(tz);
    const float wx = tx - fx, wy = ty - fy, wz = tz - fz;
    const unsigned ix = (unsigned)(int)fx;
    const unsigned iy = (unsigned)(int)fy;
    const unsigned iz = (unsigned)(int)fz;
    const unsigned hy0 = iy * 2654435761u, hy1 = hy0 + 2654435761u;
    const unsigned hz0 = iz * 805459861u,  hz1 = hz0 + 805459861u;
    const unsigned ix1 = ix + 1u;

    const float2* tb = (const float2*)tables + (size_t)l * TBL;
    const float2 e000 = tb[(ix  ^ hy0 ^ hz0) & TMASK];
    const float2 e001 = tb[(ix  ^ hy0 ^ hz1) & TMASK];
    const float2 e010 = tb[(ix  ^ hy1 ^ hz0) & TMASK];
    const float2 e011 = tb[(ix  ^ hy1 ^ hz1) & TMASK];
    const float2 e100 = tb[(ix1 ^ hy0 ^ hz0) & TMASK];
    const float2 e101 = tb[(ix1 ^ hy0 ^ hz1) & TMASK];
    const float2 e110 = tb[(ix1 ^ hy1 ^ hz0) & TMASK];
    const float2 e111 = tb[(ix1 ^ hy1 ^ hz1) & TMASK];

    const float ux = 1.f - wx, uy = 1.f - wy, uz = 1.f - wz;
    const float c000 = ux * uy * uz, c001 = ux * uy * wz;
    const float c010 = ux * wy * uz, c011 = ux * wy * wz;
    const float c100 = wx * uy * uz, c101 = wx * uy * wz;
    const float c110 = wx * wy * uz, c111 = wx * wy * wz;

    float f0 = e000.x * c000, f1 = e000.y * c000;
    f0 = fmaf(e001.x, c001, f0); f1 = fmaf(e001.y, c001, f1);
    f0 = fmaf(e010.x, c010, f0); f1 = fmaf(e010.y, c010, f1);
    f0 = fmaf(e011.x, c011, f0); f1 = fmaf(e011.y, c011, f1);
    f0 = fmaf(e100.x, c100, f0); f1 = fmaf(e100.y, c100, f1);
    f0 = fmaf(e101.x, c101, f0); f1 = fmaf(e101.y, c101, f1);
    f0 = fmaf(e110.x, c110, f0); f1 = fmaf(e110.y, c110, f1);
    f0 = fmaf(e111.x, c111, f0); f1 = fmaf(e111.y, c111, f1);

    ws2[(size_t)l * n + idx] = make_float2(f0, f1);
}

// ------------------------------------------------------------------
// Kernel 2: split-precision MFMA MLP, persistent blocks.
// Grid = 512 blocks (2/CU, one co-residency round); each stages
// weights ONCE then loops GROUPS=16 point-groups of 64.
// R10: next-group ws2/dirp prefetched into registers; group loop
// forced to unroll 1 (I$: one ~3 KB body, not 16 copies).
// Inner math identical to R8/R9 (proven, absmax 3.9e-3).
// ------------------------------------------------------------------
#define MT   256
#define GROUPS 16
#define SW1  32                  // Wd1 k-stride (shorts), rows 16B-aligned
#define SW   72                  // 64-k weight stride (shorts), rows 16B-aligned
#define SA   66                  // act k-stride (floats)
#define OW1  0                   // 64*32 = 2048
#define OW2  2048                // 16*72 = 1152
#define OC1H 3200                // 64*72 = 4608
#define OC1L 7808
#define OC2H 12416
#define OC2L 17024
#define OC3H 21632               // 16*72 = 1152
#define OC3L 22784
#define WTOT 23936               // shorts = 47872 B; + act 16896 B = 64768 B

__global__ __launch_bounds__(256, 2)
void ngp_mlp_mfma4(const float2* __restrict__ ws2,
                   const float* __restrict__ dirp,
                   const float* __restrict__ Wd1, const float* __restrict__ bd1,
                   const float* __restrict__ Wd2, const float* __restrict__ bd2,
                   const float* __restrict__ Wc1, const float* __restrict__ bc1,
                   const float* __restrict__ Wc2, const float* __restrict__ bc2,
                   const float* __restrict__ Wc3, const float* __restrict__ bc3,
                   float* __restrict__ out, int n)
{
    __shared__ short wsm[WTOT];
    __shared__ float act[4 * 16 * SA];
    const int tid = threadIdx.x;

    for (int t = tid; t < WTOT; t += MT) wsm[t] = 0;
    __syncthreads();

    for (int g = tid; g < 32 * 64; g += MT) {            // Wd1 (32,64) single
        const int k = g >> 6, nn = g & 63;
        wsm[OW1 + nn * SW1 + k] = f2bf(Wd1[g]);
    }
    for (int g = tid; g < 64 * 16; g += MT) {            // Wd2 (64,16) single
        const int k = g >> 4, nn = g & 15;
        wsm[OW2 + nn * SW + k] = f2bf(Wd2[g]);
    }
    for (int g = tid; g < 41 * 64; g += MT) {            // Wc1 (41,64) hi+lo
        const int k = g >> 6, nn = g & 63;
        const float w = Wc1[g];
        const unsigned short hh = f2bf(w);
        wsm[OC1H + nn * SW + k] = hh;
        wsm[OC1L + nn * SW + k] = f2bf(w - b2f(hh));
    }
    for (int g = tid; g < 64 * 64; g += MT) {            // Wc2 (64,64) hi+lo
        const int k = g >> 6, nn = g & 63;
        const float w = Wc2[g];
        const unsigned short hh = f2bf(w);
        wsm[OC2H + nn * SW + k] = hh;
        wsm[OC2L + nn * SW + k] = f2bf(w - b2f(hh));
    }
    for (int g = tid; g < 64 * 3; g += MT) {             // Wc3 (64,3) hi+lo
        const int k = g / 3, nn = g - 3 * k;
        const float w = Wc3[g];
        const unsigned short hh = f2bf(w);
        wsm[OC3H + nn * SW + k] = hh;
        wsm[OC3L + nn * SW + k] = f2bf(w - b2f(hh));
    }
    __syncthreads();

    const int wid = tid >> 6;
    const int lane = tid & 63;
    const int ln = lane & 15;
    const int qd = lane >> 4;
    float* A = act + wid * (16 * SA);

#define LOAD_SPLIT(ah, al, k0)                                   \
    {                                                            \
        _Pragma("unroll")                                        \
        for (int j = 0; j < 8; ++j) {                            \
            const float v = A[ln * SA + (k0) + j];               \
            const unsigned short hb = f2bf(v);                   \
            ah[j] = (short)hb;                                   \
            al[j] = (short)f2bf(v - b2f(hb));                    \
        }                                                        \
    }

#define SPLIT_TILE(acc, ah0, ah1, al0, al1, OH, OL, row)                                          \
    {                                                                                             \
        const bf16x8 bh0 = *(const bf16x8*)&wsm[(OH) + (row) * SW + qd * 8];                      \
        const bf16x8 bh1 = *(const bf16x8*)&wsm[(OH) + (row) * SW + 32 + qd * 8];                 \
        const bf16x8 bl0 = *(const bf16x8*)&wsm[(OL) + (row) * SW + qd * 8];                      \
        const bf16x8 bl1 = *(const bf16x8*)&wsm[(OL) + (row) * SW + 32 + qd * 8];                 \
        acc = __builtin_amdgcn_mfma_f32_16x16x32_bf16(ah0, bh0, acc, 0, 0, 0);                    \
        acc = __builtin_amdgcn_mfma_f32_16x16x32_bf16(ah1, bh1, acc, 0, 0, 0);                    \
        acc = __builtin_amdgcn_mfma_f32_16x16x32_bf16(al0, bh0, acc, 0, 0, 0);                    \
        acc = __builtin_amdgcn_mfma_f32_16x16x32_bf16(al1, bh1, acc, 0, 0, 0);                    \
        acc = __builtin_amdgcn_mfma_f32_16x16x32_bf16(ah0, bl0, acc, 0, 0, 0);                    \
        acc = __builtin_amdgcn_mfma_f32_16x16x32_bf16(ah1, bl1, acc, 0, 0, 0);                    \
    }

    // ---- register prefetch of group 0's globals ----
    const int pt0 = blockIdx.x * (GROUPS * 64) + wid * 16 + ln;
    float2 xq0, xq1, xq2, xq3;
    float dq0, dq1, dq2;
    xq0 = ws2[(size_t)(qd * 4 + 0) * n + pt0];
    xq1 = ws2[(size_t)(qd * 4 + 1) * n + pt0];
    xq2 = ws2[(size_t)(qd * 4 + 2) * n + pt0];
    xq3 = ws2[(size_t)(qd * 4 + 3) * n + pt0];
    dq0 = dirp[3 * pt0 + 0];
    dq1 = dirp[3 * pt0 + 1];
    dq2 = dirp[3 * pt0 + 2];

#pragma unroll 1
    for (int grp = 0; grp < GROUPS; ++grp) {
        const int pt_base = blockIdx.x * (GROUPS * 64) + grp * 64 + wid * 16;
        const int pt = pt_base + ln;

        // consume prefetched globals
        bf16x8 ax;
        ax[0] = (short)f2bf(xq0.x); ax[1] = (short)f2bf(xq0.y);
        ax[2] = (short)f2bf(xq1.x); ax[3] = (short)f2bf(xq1.y);
        ax[4] = (short)f2bf(xq2.x); ax[5] = (short)f2bf(xq2.y);
        ax[6] = (short)f2bf(xq3.x); ax[7] = (short)f2bf(xq3.y);
        const float ddx = dq0, ddy = dq1, ddz = dq2;

        // issue next group's globals now (consumed next iteration)
        if (grp + 1 < GROUPS) {
            const int ptn = pt + 64;
            xq0 = ws2[(size_t)(qd * 4 + 0) * n + ptn];
            xq1 = ws2[(size_t)(qd * 4 + 1) * n + ptn];
            xq2 = ws2[(size_t)(qd * 4 + 2) * n + ptn];
            xq3 = ws2[(size_t)(qd * 4 + 3) * n + ptn];
            dq0 = dirp[3 * ptn + 0];
            dq1 = dirp[3 * ptn + 1];
            dq2 = dirp[3 * ptn + 2];
        }

        // ---- d1: Y[16x64] = X @ Wd1 (single bf16) ----
        f32x4 yacc[4];
#pragma unroll
        for (int t = 0; t < 4; ++t) {
            const bf16x8 b = *(const bf16x8*)&wsm[OW1 + (t * 16 + ln) * SW1 + qd * 8];
            const float bv = bd1[t * 16 + ln];
            f32x4 acc = {bv, bv, bv, bv};
            yacc[t] = __builtin_amdgcn_mfma_f32_16x16x32_bf16(ax, b, acc, 0, 0, 0);
        }
#pragma unroll
        for (int t = 0; t < 4; ++t)
#pragma unroll
            for (int r = 0; r < 4; ++r)
                A[(qd * 4 + r) * SA + t * 16 + ln] = fmaxf(yacc[t][r], 0.f);   // fp32

        // ---- d2: D[16x16] = relu(Y) @ Wd2 (single bf16) ----
        {
            bf16x8 a0, a1;
#pragma unroll
            for (int j = 0; j < 8; ++j) a0[j] = (short)f2bf(A[ln * SA + qd * 8 + j]);
#pragma unroll
            for (int j = 0; j < 8; ++j) a1[j] = (short)f2bf(A[ln * SA + 32 + qd * 8 + j]);
            const bf16x8 b0 = *(const bf16x8*)&wsm[OW2 + ln * SW + qd * 8];
            const bf16x8 b1 = *(const bf16x8*)&wsm[OW2 + ln * SW + 32 + qd * 8];
            const float bv = bd2[ln];
            f32x4 acc = {bv, bv, bv, bv};
            acc = __builtin_amdgcn_mfma_f32_16x16x32_bf16(a0, b0, acc, 0, 0, 0);
            acc = __builtin_amdgcn_mfma_f32_16x16x32_bf16(a1, b1, acc, 0, 0, 0);
            if (ln == 15) {
#pragma unroll
                for (int r = 0; r < 4; ++r)
                    out[3 * n + pt_base + qd * 4 + r] = fmaxf(acc[r], 0.f);    // sigma
            }
#pragma unroll
            for (int r = 0; r < 4; ++r)
                A[(qd * 4 + r) * SA + ln] = acc[r];        // raw D fp32, k=0..15
        }

        // ---- SH -> act fp32, k=16..40 (k=41..63 stale, Wc1 rows zeroed) ----
        {
            float sh[25];
            SH_BLOCK(sh, ddx, ddy, ddz)
            for (int i = qd; i < 25; i += 4)
                A[ln * SA + 16 + i] = sh[i];
        }

        // ---- c1: H1 = [D|SH|0] @ Wc1 (split) ----
        {
            bf16x8 ah0, ah1, al0, al1;
            LOAD_SPLIT(ah0, al0, qd * 8)
            LOAD_SPLIT(ah1, al1, 32 + qd * 8)
            f32x4 hacc[4];
#pragma unroll
            for (int t = 0; t < 4; ++t) {
                const float bv = bc1[t * 16 + ln];
                f32x4 acc = {bv, bv, bv, bv};
                SPLIT_TILE(acc, ah0, ah1, al0, al1, OC1H, OC1L, t * 16 + ln)
                hacc[t] = acc;
            }
#pragma unroll
            for (int t = 0; t < 4; ++t)
#pragma unroll
                for (int r = 0; r < 4; ++r)
                    A[(qd * 4 + r) * SA + t * 16 + ln] = fmaxf(hacc[t][r], 0.f);
        }

        // ---- c2: H2 = relu(H1) @ Wc2 (split) ----
        {
            bf16x8 ah0, ah1, al0, al1;
            LOAD_SPLIT(ah0, al0, qd * 8)
            LOAD_SPLIT(ah1, al1, 32 + qd * 8)
            f32x4 hacc[4];
#pragma unroll
            for (int t = 0; t < 4; ++t) {
                const float bv = bc2[t * 16 + ln];
                f32x4 acc = {bv, bv, bv, bv};
                SPLIT_TILE(acc, ah0, ah1, al0, al1, OC2H, OC2L, t * 16 + ln)
                hacc[t] = acc;
            }
#pragma unroll
            for (int t = 0; t < 4; ++t)
#pragma unroll
                for (int r = 0; r < 4; ++r)
                    A[(qd * 4 + r) * SA + t * 16 + ln] = fmaxf(hacc[t][r], 0.f);
        }

        // ---- c3 + sigmoid: R = relu(H2) @ Wc3 (split) ----
        {
            bf16x8 ah0, ah1, al0, al1;
            LOAD_SPLIT(ah0, al0, qd * 8)
            LOAD_SPLIT(ah1, al1, 32 + qd * 8)
            const float bv = (ln < 3) ? bc3[ln] : 0.f;
            f32x4 acc = {bv, bv, bv, bv};
            SPLIT_TILE(acc, ah0, ah1, al0, al1, OC3H, OC3L, ln)
            if (ln < 3) {
#pragma unroll
                for (int r = 0; r < 4; ++r)
                    out[3 * (pt_base + qd * 4 + r) + ln] = 1.f / (1.f + expf(-acc[r]));
            }
        }
    }
}

// ------------------------------------------------------------------
// Fallback: round-1 fused kernel (if ws too small / n not 2^19) — proven
// ------------------------------------------------------------------
__global__ __launch_bounds__(256)
void nerf_fused(const float* __restrict__ pos,
                const float* __restrict__ dirp,
                const float* __restrict__ tables,
                const float* __restrict__ Wd1, const float* __restrict__ bd1,
                const float* __restrict__ Wd2, const float* __restrict__ bd2,
                const float* __restrict__ Wc1, const float* __restrict__ bc1,
                const float* __restrict__ Wc2, const float* __restrict__ bc2,
                const float* __restrict__ Wc3, const float* __restrict__ bc3,
                float* __restrict__ out, int n)
{
    const int idx = blockIdx.x * blockDim.x + threadIdx.x;
    if (idx >= n) return;
    const float px = pos[3 * idx + 0], py = pos[3 * idx + 1], pz = pos[3 * idx + 2];
    float y[64];
#pragma unroll
    for (int j = 0; j < 64; ++j) y[j] = bd1[j];
#pragma unroll
    for (int l = 0; l < LEVELS; ++l) {
        const float resf = (float)(16 << l);
        const float tx = px * resf, ty = py * resf, tz = pz * resf;
        const float fx = floorf(tx), fy = floorf(ty), fz = floorf(tz);
        const float wx = tx - fx, wy = ty - fy, wz = tz - fz;
        const unsigned ix = (unsigned)(int)fx, iy = (unsigned)(int)fy, iz = (unsigned)(int)fz;
        const unsigned hy0 = iy * 2654435761u, hy1 = hy0 + 2654435761u;
        const unsigned hz0 = iz * 805459861u,  hz1 = hz0 + 805459861u;
        const unsigned ix1 = ix + 1u;
        const float2* tb = (const float2*)tables + (size_t)l * TBL;
        const float2 e000 = tb[(ix  ^ hy0 ^ hz0) & TMASK];
        const float2 e001 = tb[(ix  ^ hy0 ^ hz1) & TMASK];
        const float2 e010 = tb[(ix  ^ hy1 ^ hz0) & TMASK];
        const float2 e011 = tb[(ix  ^ hy1 ^ hz1) & TMASK];
        const float2 e100 = tb[(ix1 ^ hy0 ^ hz0) & TMASK];
        const float2 e101 = tb[(ix1 ^ hy0 ^ hz1) & TMASK];
        const float2 e110 = tb[(ix1 ^ hy1 ^ hz0) & TMASK];
        const float2 e111 = tb[(ix1 ^ hy1 ^ hz1) & TMASK];
        const float ux = 1.f - wx, uy = 1.f - wy, uz = 1.f - wz;
        const float c000 = ux*uy*uz, c001 = ux*uy*wz, c010 = ux*wy*uz, c011 = ux*wy*wz;
        const float c100 = wx*uy*uz, c101 = wx*uy*wz, c110 = wx*wy*uz, c111 = wx*wy*wz;
        float f0 = e000.x*c000, f1 = e000.y*c000;
        f0 = fmaf(e001.x,c001,f0); f1 = fmaf(e001.y,c001,f1);
        f0 = fmaf(e010.x,c010,f0); f1 = fmaf(e010.y,c010,f1);
        f0 = fmaf(e011.x,c011,f0); f1 = fmaf(e011.y,c011,f1);
        f0 = fmaf(e100.x,c100,f0); f1 = fmaf(e100.y,c100,f1);
        f0 = fmaf(e101.x,c101,f0); f1 = fmaf(e101.y,c101,f1);
        f0 = fmaf(e110.x,c110,f0); f1 = fmaf(e110.y,c110,f1);
        f0 = fmaf(e111.x,c111,f0); f1 = fmaf(e111.y,c111,f1);
        const float* w0 = Wd1 + (size_t)(2 * l) * 64;
#pragma unroll
        for (int j = 0; j < 64; ++j)
            y[j] = fmaf(f0, w0[j], fmaf(f1, w0[64 + j], y[j]));
    }
    float d[16];
#pragma unroll
    for (int k = 0; k < 16; ++k) d[k] = bd2[k];
#pragma unroll
    for (int j = 0; j < 64; ++j) {
        const float a = fmaxf(y[j], 0.f);
#pragma unroll
        for (int k = 0; k < 16; ++k) d[k] = fmaf(a, Wd2[j * 16 + k], d[k]);
    }
    out[3 * n + idx] = fmaxf(d[15], 0.f);
    const float dx = dirp[3*idx], dy = dirp[3*idx+1], dz = dirp[3*idx+2];
    float sh[25];
    SH_BLOCK(sh, dx, dy, dz)
    float h1[64];
#pragma unroll
    for (int j = 0; j < 64; ++j) h1[j] = bc1[j];
#pragma unroll
    for (int i = 0; i < 16; ++i) {
#pragma unroll
        for (int j = 0; j < 64; ++j) h1[j] = fmaf(d[i], Wc1[i * 64 + j], h1[j]);
    }
#pragma unroll
    for (int s = 0; s < 25; ++s) {
#pragma unroll
        for (int j = 0; j < 64; ++j) h1[j] = fmaf(sh[s], Wc1[(16 + s) * 64 + j], h1[j]);
    }
    float h2[64];
#pragma unroll
    for (int j = 0; j < 64; ++j) h2[j] = bc2[j];
#pragma unroll
    for (int i = 0; i < 64; ++i) {
        const float a = fmaxf(h1[i], 0.f);
#pragma unroll
        for (int j = 0; j < 64; ++j) h2[j] = fmaf(a, Wc2[i * 64 + j], h2[j]);
    }
    float r0 = bc3[0], r1 = bc3[1], r2 = bc3[2];
#pragma unroll
    for (int j = 0; j < 64; ++j) {
        const float a = fmaxf(h2[j], 0.f);
        r0 = fmaf(a, Wc3[j * 3 + 0], r0);
        r1 = fmaf(a, Wc3[j * 3 + 1], r1);
        r2 = fmaf(a, Wc3[j * 3 + 2], r2);
    }
    out[3 * idx + 0] = 1.f / (1.f + expf(-r0));
    out[3 * idx + 1] = 1.f / (1.f + expf(-r1));
    out[3 * idx + 2] = 1.f / (1.f + expf(-r2));
}

extern "C" void kernel_launch(void* const* d_in, const int* in_sizes, int n_in,
                              void* d_out, int out_size, void* d_ws, size_t ws_size,
                              hipStream_t stream) {
    const float* pos    = (const float*)d_in[0];
    const float* dir    = (const float*)d_in[1];
    const float* tables = (const float*)d_in[2];
    const float* Wd1 = (const float*)d_in[3];
    const float* bd1 = (const float*)d_in[4];
    const float* Wd2 = (const float*)d_in[5];
    const float* bd2 = (const float*)d_in[6];
    const float* Wc1 = (const float*)d_in[7];
    const float* bc1 = (const float*)d_in[8];
    const float* Wc2 = (const float*)d_in[9];
    const float* bc2 = (const float*)d_in[10];
    const float* Wc3 = (const float*)d_in[11];
    const float* bc3 = (const float*)d_in[12];

    const int n = in_sizes[0] / 3;
    const int blocks = (n + 255) / 256;
    const size_t need = (size_t)n * 128;   // 16 float2 planes = 32 floats/point

    if (ws_size >= need && n == 524288) {
        ngp_encode_lvl<<<16 * blocks, 256, 0, stream>>>(pos, tables, (float2*)d_ws, n);
        ngp_mlp_mfma4<<<n / (64 * GROUPS), 256, 0, stream>>>((const float2*)d_ws, dir,
                                                             Wd1, bd1, Wd2, bd2,
                                                             Wc1, bc1, Wc2, bc2, Wc3, bc3,
                                                             (float*)d_out, n);
    } else {
        nerf_fused<<<blocks, 256, 0, stream>>>(pos, dir, tables,
                                               Wd1, bd1, Wd2, bd2,
                                               Wc1, bc1, Wc2, bc2, Wc3, bc3,
                                               (float*)d_out, n);
    }
}